// Round 1
// baseline (537.461 us; speedup 1.0000x reference)
//
#include <hip/hip_runtime.h>
#include <hip/hip_bf16.h>
#include <math.h>

// Problem: B=256, N_SRC=10 triplets/sample, NMC=16, L=128.
// out[b, ch, y, x]: ch 0..15 = 1-z, ch 16..31 = z, z=1 at scattered cells.
//
// Round 11: single-stream plane-per-block restructure.
// Previous (round 10, 532us): one block per (b,m) writing BOTH the 1-z and z
// planes (two streams 512KB apart, alternating per unrolled store). This
// round: one block per (b,ch) writing ONE contiguous plane; consecutive
// blocks sweep the output linearly like the 6.2TB/s poison fill does.
// Numerics, dtype detection, lows/highs classification, and host binding
// are IDENTICAL to the round-8/10 verified logic (absmax 0.0):
//  * in_sizes width-proof (int32 validated all>=1, else int64, else dict).
//  * np reference on ml_dtypes bf16 inputs with PER-OP rounding:
//    mass bin = floor(16*bf16(bf16(log10 m)/bf16(3))).
#define NSRC 10
#define NMC  16
#define LSZ  128
#define PLANE (LSZ * LSZ)   // 16384

typedef unsigned int uintv4 __attribute__((ext_vector_type(4)));
typedef float        fltv4  __attribute__((ext_vector_type(4)));

__device__ __forceinline__ float bf16f(unsigned short h) {
    union { unsigned int u; float f; } c;
    c.u = ((unsigned int)h) << 16;
    return c.f;
}

// f32 -> bf16 round-to-nearest-even, returned as f32 (ml_dtypes semantics).
__device__ __forceinline__ float bf16r(float f) {
    union { float f; unsigned int u; } c;
    c.f = f;
    unsigned int lsb = (c.u >> 16) & 1u;
    c.u += 0x7FFFu + lsb;
    c.u &= 0xFFFF0000u;
    return c.f;
}

// One block per (b, ch) plane: ch<NMC -> 1-z plane for m=ch; ch>=NMC -> z
// plane for m=ch-NMC. Disjoint plane ownership -> no races, one kernel,
// and each block's stores are a single contiguous 32KB (bf16) / 64KB (f32)
// linear stream (fill-like), instead of two interleaved streams 512KB apart.
extern "C" __global__ __launch_bounds__(256)
void CustomParameterTransform_2491081031994_kernel(
    const void* __restrict__ coord_v,
    const void* __restrict__ pA,      // one of {lows, highs} — value-classified
    const void* __restrict__ pB,      // the other
    void* __restrict__ out_v)
{
    const int blk = blockIdx.x;
    const int b   = blk >> 5;              // / (2*NMC)
    const int ch  = blk & (2 * NMC - 1);   // % (2*NMC)
    const int m   = ch & (NMC - 1);
    const bool isZ = ch >= NMC;            // z plane vs 1-z plane

    // --- uniform input-dtype detection (unchanged from round 8) ---
    const unsigned short* cu = (const unsigned short*)coord_v;
    bool isbf = true;
    #pragma unroll
    for (int j = 2; j < 3 * NSRC; j += 3) {
        float v = bf16f(cu[j]);
        if (!(v >= 0.5f && v <= 2048.0f)) isbf = false;
    }

    // --- uniform lows/highs classification by element [2] (0.0 vs 3.0) ---
    float a2, b2;
    if (isbf) {
        a2 = bf16f(((const unsigned short*)pA)[2]);
        b2 = bf16f(((const unsigned short*)pB)[2]);
    } else {
        a2 = ((const float*)pA)[2];
        b2 = ((const float*)pB)[2];
    }
    const void* lows_v  = (a2 < b2) ? pA : pB;
    const void* highs_v = (a2 < b2) ? pB : pA;

    __shared__ int s_pos[NSRC];
    __shared__ int s_cnt;
    if (threadIdx.x == 0) s_cnt = 0;
    __syncthreads();

    if (threadIdx.x < NSRC) {
        int xi, yi, mi;
        if (isbf) {
            const unsigned short* t = cu + b * (3 * NSRC) + threadIdx.x * 3;
            float x    = bf16f(t[0]);
            float y    = bf16f(t[1]);
            float mass = bf16f(t[2]);
            const unsigned short* lw = (const unsigned short*)lows_v;
            const unsigned short* hg = (const unsigned short*)highs_v;
            float lo0 = bf16f(lw[0]), lo1 = bf16f(lw[1]), lo2 = bf16f(lw[2]);
            float hi0 = bf16f(hg[0]), hi1 = bf16f(hg[1]), hi2 = bf16f(hg[2]);
            // ml_dtypes chain, per-op bf16 rounding (identical to round 8).
            float d0 = bf16r(hi0 - lo0);
            float d1 = bf16r(hi1 - lo1);
            float d2 = bf16r(hi2 - lo2);
            float xg = bf16r(bf16r(x - lo0) / d0);
            float yg = bf16r(bf16r(y - lo1) / d1);
            float l10 = bf16r((float)log10((double)mass));
            float mg  = bf16r(bf16r(l10 - lo2) / d2);
            xi = (int)floorf(bf16r(xg * (float)LSZ));
            yi = (int)floorf(bf16r(yg * (float)LSZ));
            mi = (int)floorf(bf16r(mg * (float)NMC));
        } else {
            const float* cf = (const float*)coord_v;
            const float* t = cf + b * (3 * NSRC) + threadIdx.x * 3;
            const float* lw = (const float*)lows_v;
            const float* hg = (const float*)highs_v;
            float xg = (t[0] - lw[0]) / (hg[0] - lw[0]);
            float yg = (t[1] - lw[1]) / (hg[1] - lw[1]);
            float mg = ((float)log10((double)t[2]) - lw[2]) / (hg[2] - lw[2]);
            xi = (int)floorf(xg * (float)LSZ);
            yi = (int)floorf(yg * (float)LSZ);
            mi = (int)floorf(mg * (float)NMC);
        }
        if (mi == m && (unsigned)xi < (unsigned)LSZ && (unsigned)yi < (unsigned)LSZ) {
            int slot = atomicAdd(&s_cnt, 1);
            s_pos[slot] = yi * LSZ + xi;
        }
    }
    __syncthreads();
    const int cnt = s_cnt;             // block-uniform, typically 0 or 1

    if (isbf) {
        unsigned short* p = (unsigned short*)out_v
                          + ((size_t)b * (2 * NMC) + ch) * PLANE;
        const unsigned int bg = isZ ? 0u : 0x3F803F80u;   // background pattern
        if (cnt == 0) {
            // Fast path (most blocks): one contiguous constant stream.
            const uintv4 v = { bg, bg, bg, bg };
            #pragma unroll
            for (int k = 0; k < PLANE / (256 * 8); ++k) {
                __builtin_nontemporal_store(
                    v, (uintv4*)(p + threadIdx.x * 8 + k * 256 * 8));
            }
        } else {
            #pragma unroll
            for (int k = 0; k < PLANE / (256 * 8); ++k) {
                const int base = threadIdx.x * 8 + k * 256 * 8;
                // Static-component predicated masks — no arrays, no unions.
                unsigned int z0 = 0, z1 = 0, z2 = 0, z3 = 0;
                for (int j = 0; j < cnt; ++j) {
                    int d = s_pos[j] - base;
                    z0 |= (d == 0) ? 0x3F80u : 0u;  z0 |= (d == 1) ? 0x3F800000u : 0u;
                    z1 |= (d == 2) ? 0x3F80u : 0u;  z1 |= (d == 3) ? 0x3F800000u : 0u;
                    z2 |= (d == 4) ? 0x3F80u : 0u;  z2 |= (d == 5) ? 0x3F800000u : 0u;
                    z3 |= (d == 6) ? 0x3F80u : 0u;  z3 |= (d == 7) ? 0x3F800000u : 0u;
                }
                // Each bf16 half is exactly 0x0000 or 0x3F80:
                //   z plane  (bg=0):          v = z
                //   1-z plane (bg=0x3F803F80): v = z ^ bg  (ones, 0 at hits)
                uintv4 v = { z0 ^ bg, z1 ^ bg, z2 ^ bg, z3 ^ bg };
                __builtin_nontemporal_store(v, (uintv4*)(p + base));
            }
        }
    } else {
        float* p = (float*)out_v + ((size_t)b * (2 * NMC) + ch) * PLANE;
        const float bgf = isZ ? 0.f : 1.f;
        if (cnt == 0) {
            const fltv4 v = { bgf, bgf, bgf, bgf };
            #pragma unroll
            for (int k = 0; k < PLANE / (256 * 4); ++k) {
                __builtin_nontemporal_store(
                    v, (fltv4*)(p + threadIdx.x * 4 + k * 256 * 4));
            }
        } else {
            #pragma unroll
            for (int k = 0; k < PLANE / (256 * 4); ++k) {
                const int base = threadIdx.x * 4 + k * 256 * 4;
                float zx = 0.f, zy = 0.f, zz = 0.f, zw = 0.f;
                for (int j = 0; j < cnt; ++j) {
                    int d = s_pos[j] - base;
                    zx = (d == 0) ? 1.f : zx;
                    zy = (d == 1) ? 1.f : zy;
                    zz = (d == 2) ? 1.f : zz;
                    zw = (d == 3) ? 1.f : zw;
                }
                fltv4 v;
                if (isZ) v = (fltv4){ zx, zy, zz, zw };
                else     v = (fltv4){ 1.f - zx, 1.f - zy, 1.f - zz, 1.f - zw };
                __builtin_nontemporal_store(v, (fltv4*)(p + base));
            }
        }
    }
}

// Validate a candidate size vector {..,30*nb,..,3,..,3,..,1,1}. Requires
// ALL entries >= 1 — rejects the int32 view of 64-bit sizes (contains
// zeros), disambiguating the integer width. (Identical to round 8.)
static bool try_bind(const long* v, int n, int& ic, int& iA, int& iB, long& nbc) {
    for (int i = 0; i < n; ++i) if (v[i] < 1) return false;
    int lc = -1, a = -1, b = -1;
    for (int i = 0; i < n; ++i)
        if (v[i] >= 30 && v[i] % 30 == 0) { if (lc >= 0) return false; lc = i; }
    if (lc < 0) return false;
    for (int i = 0; i < n; ++i) {
        if (i == lc) continue;
        if (v[i] == 3) { if (a < 0) a = i; else if (b < 0) b = i; else return false; }
    }
    if (a < 0 || b < 0) return false;
    ic = lc; iA = a; iB = b; nbc = v[lc] / 30;
    return true;
}

extern "C" void kernel_launch(void* const* d_in, const int* in_sizes, int n_in,
                              void* d_out, int out_size, void* d_ws, size_t ws_size,
                              hipStream_t stream) {
    int ic = 0, iA = 1, iB = 2;       // dict-order fallback
    long nbc = -1;
    const int n = (n_in > 8) ? 8 : (n_in > 0 ? n_in : 0);
    long v[8];
    bool ok = false;
    if (n >= 3) {
        for (int i = 0; i < n; ++i) v[i] = (long)in_sizes[i];
        ok = try_bind(v, n, ic, iA, iB, nbc);              // int32 sizes
        if (!ok) {
            const long long* s64 = (const long long*)in_sizes;
            for (int i = 0; i < n; ++i) v[i] = (long)s64[i];
            ok = try_bind(v, n, ic, iA, iB, nbc);          // int64 sizes
        }
        if (!ok) { ic = 0; iA = 1; iB = 2; nbc = -1; }     // dict order
    }

    // n_batch: validated coord count, cross-checked vs out_size as element
    // count ([nb, 2*NMC, L, L]); take min (bytes-vs-elements safe).
    long nb_out = (out_size > 0) ? (long)out_size / (2L * NMC * PLANE) : -1;
    long nb = (nbc > 0) ? nbc : nb_out;
    if (nbc > 0 && nb_out > 0 && nb_out < nb) nb = nb_out;
    if (nb <= 0) nb = 1;

    dim3 grid((unsigned)(nb * 2 * NMC));   // one block per (b, ch) plane
    dim3 block(256);
    CustomParameterTransform_2491081031994_kernel<<<grid, block, 0, stream>>>(
        d_in[ic], d_in[iA], d_in[iB], d_out);
}

// Round 2
// 534.809 us; speedup vs baseline: 1.0050x; 1.0050x over previous
//
#include <hip/hip_runtime.h>
#include <hip/hip_bf16.h>
#include <math.h>

// Problem: B=256, N_SRC=10 triplets/sample, NMC=16, L=128.
// out[b, ch, y, x]: ch 0..15 = 1-z, ch 16..31 = z, z=1 at scattered cells.
//
// Round 12: A/B — regular (temporal) stores instead of nontemporal.
// Round-11 null result (plane-per-block, single linear stream per block:
// 537us vs 532us) falsified the dual-stream theory. The store loop now
// matches the 6.3TB/s poison fill in every structural respect EXCEPT the
// nt cache-policy flag. This round removes nt, changing nothing else.
// Numerics, dtype detection, lows/highs classification, and host binding
// are IDENTICAL to the verified round-8/10/11 logic (absmax 0.0):
//  * in_sizes width-proof (int32 validated all>=1, else int64, else dict).
//  * np reference on ml_dtypes bf16 inputs with PER-OP rounding:
//    mass bin = floor(16*bf16(bf16(log10 m)/bf16(3))).
#define NSRC 10
#define NMC  16
#define LSZ  128
#define PLANE (LSZ * LSZ)   // 16384

typedef unsigned int uintv4 __attribute__((ext_vector_type(4)));
typedef float        fltv4  __attribute__((ext_vector_type(4)));

__device__ __forceinline__ float bf16f(unsigned short h) {
    union { unsigned int u; float f; } c;
    c.u = ((unsigned int)h) << 16;
    return c.f;
}

// f32 -> bf16 round-to-nearest-even, returned as f32 (ml_dtypes semantics).
__device__ __forceinline__ float bf16r(float f) {
    union { float f; unsigned int u; } c;
    c.f = f;
    unsigned int lsb = (c.u >> 16) & 1u;
    c.u += 0x7FFFu + lsb;
    c.u &= 0xFFFF0000u;
    return c.f;
}

// One block per (b, ch) plane: ch<NMC -> 1-z plane for m=ch; ch>=NMC -> z
// plane for m=ch-NMC. Disjoint plane ownership -> no races, one kernel,
// each block's stores are a single contiguous 32KB (bf16) / 64KB (f32)
// linear stream, consecutive blocks sweep the output linearly (fill-like).
extern "C" __global__ __launch_bounds__(256)
void CustomParameterTransform_2491081031994_kernel(
    const void* __restrict__ coord_v,
    const void* __restrict__ pA,      // one of {lows, highs} — value-classified
    const void* __restrict__ pB,      // the other
    void* __restrict__ out_v)
{
    const int blk = blockIdx.x;
    const int b   = blk >> 5;              // / (2*NMC)
    const int ch  = blk & (2 * NMC - 1);   // % (2*NMC)
    const int m   = ch & (NMC - 1);
    const bool isZ = ch >= NMC;            // z plane vs 1-z plane

    // --- uniform input-dtype detection (unchanged from round 8) ---
    const unsigned short* cu = (const unsigned short*)coord_v;
    bool isbf = true;
    #pragma unroll
    for (int j = 2; j < 3 * NSRC; j += 3) {
        float v = bf16f(cu[j]);
        if (!(v >= 0.5f && v <= 2048.0f)) isbf = false;
    }

    // --- uniform lows/highs classification by element [2] (0.0 vs 3.0) ---
    float a2, b2;
    if (isbf) {
        a2 = bf16f(((const unsigned short*)pA)[2]);
        b2 = bf16f(((const unsigned short*)pB)[2]);
    } else {
        a2 = ((const float*)pA)[2];
        b2 = ((const float*)pB)[2];
    }
    const void* lows_v  = (a2 < b2) ? pA : pB;
    const void* highs_v = (a2 < b2) ? pB : pA;

    __shared__ int s_pos[NSRC];
    __shared__ int s_cnt;
    if (threadIdx.x == 0) s_cnt = 0;
    __syncthreads();

    if (threadIdx.x < NSRC) {
        int xi, yi, mi;
        if (isbf) {
            const unsigned short* t = cu + b * (3 * NSRC) + threadIdx.x * 3;
            float x    = bf16f(t[0]);
            float y    = bf16f(t[1]);
            float mass = bf16f(t[2]);
            const unsigned short* lw = (const unsigned short*)lows_v;
            const unsigned short* hg = (const unsigned short*)highs_v;
            float lo0 = bf16f(lw[0]), lo1 = bf16f(lw[1]), lo2 = bf16f(lw[2]);
            float hi0 = bf16f(hg[0]), hi1 = bf16f(hg[1]), hi2 = bf16f(hg[2]);
            // ml_dtypes chain, per-op bf16 rounding (identical to round 8).
            float d0 = bf16r(hi0 - lo0);
            float d1 = bf16r(hi1 - lo1);
            float d2 = bf16r(hi2 - lo2);
            float xg = bf16r(bf16r(x - lo0) / d0);
            float yg = bf16r(bf16r(y - lo1) / d1);
            float l10 = bf16r((float)log10((double)mass));
            float mg  = bf16r(bf16r(l10 - lo2) / d2);
            xi = (int)floorf(bf16r(xg * (float)LSZ));
            yi = (int)floorf(bf16r(yg * (float)LSZ));
            mi = (int)floorf(bf16r(mg * (float)NMC));
        } else {
            const float* cf = (const float*)coord_v;
            const float* t = cf + b * (3 * NSRC) + threadIdx.x * 3;
            const float* lw = (const float*)lows_v;
            const float* hg = (const float*)highs_v;
            float xg = (t[0] - lw[0]) / (hg[0] - lw[0]);
            float yg = (t[1] - lw[1]) / (hg[1] - lw[1]);
            float mg = ((float)log10((double)t[2]) - lw[2]) / (hg[2] - lw[2]);
            xi = (int)floorf(xg * (float)LSZ);
            yi = (int)floorf(yg * (float)LSZ);
            mi = (int)floorf(mg * (float)NMC);
        }
        if (mi == m && (unsigned)xi < (unsigned)LSZ && (unsigned)yi < (unsigned)LSZ) {
            int slot = atomicAdd(&s_cnt, 1);
            s_pos[slot] = yi * LSZ + xi;
        }
    }
    __syncthreads();
    const int cnt = s_cnt;             // block-uniform, typically 0 or 1

    if (isbf) {
        unsigned short* p = (unsigned short*)out_v
                          + ((size_t)b * (2 * NMC) + ch) * PLANE;
        const unsigned int bg = isZ ? 0u : 0x3F803F80u;   // background pattern
        if (cnt == 0) {
            // Fast path (most blocks): one contiguous constant stream.
            const uintv4 v = { bg, bg, bg, bg };
            #pragma unroll
            for (int k = 0; k < PLANE / (256 * 8); ++k) {
                *(uintv4*)(p + threadIdx.x * 8 + k * 256 * 8) = v;
            }
        } else {
            #pragma unroll
            for (int k = 0; k < PLANE / (256 * 8); ++k) {
                const int base = threadIdx.x * 8 + k * 256 * 8;
                // Static-component predicated masks — no arrays, no unions.
                unsigned int z0 = 0, z1 = 0, z2 = 0, z3 = 0;
                for (int j = 0; j < cnt; ++j) {
                    int d = s_pos[j] - base;
                    z0 |= (d == 0) ? 0x3F80u : 0u;  z0 |= (d == 1) ? 0x3F800000u : 0u;
                    z1 |= (d == 2) ? 0x3F80u : 0u;  z1 |= (d == 3) ? 0x3F800000u : 0u;
                    z2 |= (d == 4) ? 0x3F80u : 0u;  z2 |= (d == 5) ? 0x3F800000u : 0u;
                    z3 |= (d == 6) ? 0x3F80u : 0u;  z3 |= (d == 7) ? 0x3F800000u : 0u;
                }
                // Each bf16 half is exactly 0x0000 or 0x3F80:
                //   z plane  (bg=0):           v = z
                //   1-z plane (bg=0x3F803F80): v = z ^ bg  (ones, 0 at hits)
                uintv4 v = { z0 ^ bg, z1 ^ bg, z2 ^ bg, z3 ^ bg };
                *(uintv4*)(p + base) = v;
            }
        }
    } else {
        float* p = (float*)out_v + ((size_t)b * (2 * NMC) + ch) * PLANE;
        const float bgf = isZ ? 0.f : 1.f;
        if (cnt == 0) {
            const fltv4 v = { bgf, bgf, bgf, bgf };
            #pragma unroll
            for (int k = 0; k < PLANE / (256 * 4); ++k) {
                *(fltv4*)(p + threadIdx.x * 4 + k * 256 * 4) = v;
            }
        } else {
            #pragma unroll
            for (int k = 0; k < PLANE / (256 * 4); ++k) {
                const int base = threadIdx.x * 4 + k * 256 * 4;
                float zx = 0.f, zy = 0.f, zz = 0.f, zw = 0.f;
                for (int j = 0; j < cnt; ++j) {
                    int d = s_pos[j] - base;
                    zx = (d == 0) ? 1.f : zx;
                    zy = (d == 1) ? 1.f : zy;
                    zz = (d == 2) ? 1.f : zz;
                    zw = (d == 3) ? 1.f : zw;
                }
                fltv4 v;
                if (isZ) v = (fltv4){ zx, zy, zz, zw };
                else     v = (fltv4){ 1.f - zx, 1.f - zy, 1.f - zz, 1.f - zw };
                *(fltv4*)(p + base) = v;
            }
        }
    }
}

// Validate a candidate size vector {..,30*nb,..,3,..,3,..,1,1}. Requires
// ALL entries >= 1 — rejects the int32 view of 64-bit sizes (contains
// zeros), disambiguating the integer width. (Identical to round 8.)
static bool try_bind(const long* v, int n, int& ic, int& iA, int& iB, long& nbc) {
    for (int i = 0; i < n; ++i) if (v[i] < 1) return false;
    int lc = -1, a = -1, b = -1;
    for (int i = 0; i < n; ++i)
        if (v[i] >= 30 && v[i] % 30 == 0) { if (lc >= 0) return false; lc = i; }
    if (lc < 0) return false;
    for (int i = 0; i < n; ++i) {
        if (i == lc) continue;
        if (v[i] == 3) { if (a < 0) a = i; else if (b < 0) b = i; else return false; }
    }
    if (a < 0 || b < 0) return false;
    ic = lc; iA = a; iB = b; nbc = v[lc] / 30;
    return true;
}

extern "C" void kernel_launch(void* const* d_in, const int* in_sizes, int n_in,
                              void* d_out, int out_size, void* d_ws, size_t ws_size,
                              hipStream_t stream) {
    int ic = 0, iA = 1, iB = 2;       // dict-order fallback
    long nbc = -1;
    const int n = (n_in > 8) ? 8 : (n_in > 0 ? n_in : 0);
    long v[8];
    bool ok = false;
    if (n >= 3) {
        for (int i = 0; i < n; ++i) v[i] = (long)in_sizes[i];
        ok = try_bind(v, n, ic, iA, iB, nbc);              // int32 sizes
        if (!ok) {
            const long long* s64 = (const long long*)in_sizes;
            for (int i = 0; i < n; ++i) v[i] = (long)s64[i];
            ok = try_bind(v, n, ic, iA, iB, nbc);          // int64 sizes
        }
        if (!ok) { ic = 0; iA = 1; iB = 2; nbc = -1; }     // dict order
    }

    // n_batch: validated coord count, cross-checked vs out_size as element
    // count ([nb, 2*NMC, L, L]); take min (bytes-vs-elements safe).
    long nb_out = (out_size > 0) ? (long)out_size / (2L * NMC * PLANE) : -1;
    long nb = (nbc > 0) ? nbc : nb_out;
    if (nbc > 0 && nb_out > 0 && nb_out < nb) nb = nb_out;
    if (nb <= 0) nb = 1;

    dim3 grid((unsigned)(nb * 2 * NMC));   // one block per (b, ch) plane
    dim3 block(256);
    CustomParameterTransform_2491081031994_kernel<<<grid, block, 0, stream>>>(
        d_in[ic], d_in[iA], d_in[iB], d_out);
}